// Round 14
// baseline (238.409 us; speedup 1.0000x reference)
//
#include <hip/hip_runtime.h>
#include <hip/hip_bf16.h>
#include <stdint.h>

#define B_   128
#define C_   3
#define H_   64
#define W_   64
#define KS   5
#define OC   64
#define OH   32
#define OW   32
#define PSZ  75          // C*K*K
#define FCIN 65536       // OC*OH*OW
#define HID  1536
#define NCLS 10
#define EPSV 1e-5f

typedef __attribute__((ext_vector_type(8))) short  bf16x8;
typedef __attribute__((ext_vector_type(8))) short  short8;
typedef __attribute__((ext_vector_type(4))) float  f32x4;

static __device__ __forceinline__ float bf2f(short u) {
  union { unsigned int i; float f; } v;
  v.i = ((unsigned int)(unsigned short)u) << 16;
  return v.f;
}
static __device__ __forceinline__ short f2bf(float f) {
  union { float f; unsigned int i; } v; v.f = f;
  unsigned int r = v.i + 0x7FFF + ((v.i >> 16) & 1);   // RNE
  return (short)(r >> 16);
}
static __device__ __forceinline__ float u2f(unsigned int u) {
  union { unsigned int i; float f; } v; v.i = u; return v.f;
}

// async global->LDS, 16B per lane; LDS dest is WAVE-UNIFORM base (+lane*16 by
// HW); the GLOBAL source is per-lane (supports arbitrary scatter).
static __device__ __forceinline__ void gld16(const unsigned short* g, unsigned short* l) {
  __builtin_amdgcn_global_load_lds(
      (const __attribute__((address_space(1))) unsigned int*)g,
      (__attribute__((address_space(3))) unsigned int*)l, 16, 0, 0);
}
static __device__ __forceinline__ void gld16f(const float* g, float* l) {
  __builtin_amdgcn_global_load_lds(
      (const __attribute__((address_space(1))) unsigned int*)g,
      (__attribute__((address_space(3))) unsigned int*)l, 16, 0, 0);
}

// ---------------- K1: LocallyConnected2d conv -> bf16 out [b][o][h*32+w] ----
// (R13 version -- at its LDS/VALU issue floor; do not touch)
__global__ __launch_bounds__(256, 2) void k1_conv(
    const float* __restrict__ x, const float* __restrict__ lcw,
    unsigned short* __restrict__ outb) {
  const int h  = blockIdx.x;
  const int og = blockIdx.y;
  const int zb = blockIdx.z;
  const int tid = threadIdx.x;
  const int w  = tid & 31;
  const int ot = tid >> 5;
  const int o0 = og * 16 + ot * 2;

  __shared__ unsigned short xs[16][C_][KS][72];  // bf16; gcol stored at col+2

  const float* wbaseA = lcw + (long)o0 * PSZ * 1024 + h * 32 + w;
  const float* wbaseB = wbaseA + (long)PSZ * 1024;

  const int row0 = 2 * h - 2;
  for (int g = 0; g < 2; ++g) {
    const int bg = zb * 2 + g;
    if (g) __syncthreads();

    if (tid < 240) {
      int t = tid;
      int r = t % KS;  t /= KS;
      int c = t % C_;
      int b = t / C_;
      *(unsigned int*)&xs[b][c][r][0]  = 0u;
      *(unsigned int*)&xs[b][c][r][66] = 0u;
      *(unsigned int*)&xs[b][c][r][68] = 0u;
      *(unsigned int*)&xs[b][c][r][70] = 0u;
    }
    for (int v = tid; v < 16 * C_ * KS * 16; v += 256) {
      int col4 = v & 15;
      int t    = v >> 4;
      int r    = t % KS;  t /= KS;
      int c    = t % C_;
      int b    = t / C_;
      int grow = row0 + r;
      f32x4 val = (f32x4){0.f, 0.f, 0.f, 0.f};
      if ((unsigned)grow < 64u)
        val = *(const f32x4*)&x[(((long)(bg * 16 + b) * C_ + c) * 64 + grow) * 64 + col4 * 4];
      unsigned int p0 = ((unsigned int)(unsigned short)f2bf(val[0])) |
                        (((unsigned int)(unsigned short)f2bf(val[1])) << 16);
      unsigned int p1 = ((unsigned int)(unsigned short)f2bf(val[2])) |
                        (((unsigned int)(unsigned short)f2bf(val[3])) << 16);
      *(unsigned int*)&xs[b][c][r][2 + col4 * 4]     = p0;
      *(unsigned int*)&xs[b][c][r][2 + col4 * 4 + 2] = p1;
    }
    __syncthreads();

    float acc[2][16];
    #pragma unroll
    for (int oo = 0; oo < 2; ++oo)
      #pragma unroll
      for (int b = 0; b < 16; ++b) acc[oo][b] = 0.f;

    float wA[KS], wB[KS], nA[KS], nB[KS];
    #pragma unroll
    for (int p = 0; p < KS; ++p) {
      wA[p] = wbaseA[(long)p * 1024];
      wB[p] = wbaseB[(long)p * 1024];
    }

    #pragma unroll 1
    for (int ck = 0; ck < 15; ++ck) {
      int nk = (ck + 1 < 15) ? (ck + 1) : 14;
      #pragma unroll
      for (int p = 0; p < KS; ++p) {
        nA[p] = wbaseA[((long)nk * 5 + p) * 1024];
        nB[p] = wbaseB[((long)nk * 5 + p) * 1024];
      }
      #pragma unroll
      for (int b = 0; b < 16; ++b) {
        const unsigned int* rowp =
            (const unsigned int*)(&xs[b][0][0][0] + (long)ck * 72);
        unsigned int d0 = rowp[w];
        unsigned int d1 = rowp[w + 1];
        unsigned int d2 = rowp[w + 2];
        float v0 = u2f(d0 << 16), v1 = u2f(d0 & 0xffff0000u);
        float v2 = u2f(d1 << 16), v3 = u2f(d1 & 0xffff0000u);
        float v4 = u2f(d2 << 16);
        acc[0][b] += wA[0] * v0 + wA[1] * v1 + wA[2] * v2 + wA[3] * v3 + wA[4] * v4;
        acc[1][b] += wB[0] * v0 + wB[1] * v1 + wB[2] * v2 + wB[3] * v3 + wB[4] * v4;
      }
      #pragma unroll
      for (int p = 0; p < KS; ++p) { wA[p] = nA[p]; wB[p] = nB[p]; }
    }

    #pragma unroll
    for (int oo = 0; oo < 2; ++oo)
      #pragma unroll
      for (int b = 0; b < 16; ++b)
        outb[((long)(bg * 16 + b) * OC + (o0 + oo)) * 1024 + h * 32 + w] =
            (unsigned short)f2bf(acc[oo][b]);
  }
}

// ---------------- K2: BN1 batch stats -> scale/shift per channel ------------
__global__ __launch_bounds__(1024) void k2_stats(
    const unsigned short* __restrict__ outb,
    const float* __restrict__ g, const float* __restrict__ bta,
    float* __restrict__ sc, float* __restrict__ sh) {
  const int o = blockIdx.x;
  const int tid = threadIdx.x;
  float s = 0.f, s2 = 0.f;
  const int i8 = (tid & 127) * 8;
  const int bsub = tid >> 7;
  for (int pass = 0; pass < 16; ++pass) {
    int b = bsub + pass * 8;
    const short8 v = *(const short8*)(outb + (((long)b * OC + o) << 10) + i8);
    #pragma unroll
    for (int j = 0; j < 8; ++j) { float f = bf2f(v[j]); s += f; s2 += f * f; }
  }
  #pragma unroll
  for (int off = 32; off; off >>= 1) {
    s  += __shfl_down(s, off);
    s2 += __shfl_down(s2, off);
  }
  __shared__ float ls[16], ls2[16];
  int wid = tid >> 6;
  if ((tid & 63) == 0) { ls[wid] = s; ls2[wid] = s2; }
  __syncthreads();
  if (tid == 0) {
    float ts = 0.f, ts2 = 0.f;
    for (int i = 0; i < 16; ++i) { ts += ls[i]; ts2 += ls2[i]; }
    const float inv = 1.0f / (float)(B_ * 1024);
    float mean = ts * inv;
    float var  = ts2 * inv - mean * mean;
    float rstd = 1.0f / sqrtf(var + EPSV);
    float scv  = g[o] * rstd;
    sc[o] = scv;
    sh[o] = bta[o] - mean * scv;
  }
}

// ---------------- K2.5: BN1+ReLU -> SWIZZLED packed bf16 activations --------
// Chunk layout (16B units): chunk c = kb*512 + mf*64 + lq*16 + l15
//   holds A[m = mf*16+l15][k = kb*32 + lq*8 .. +7]
__global__ __launch_bounds__(256) void k25_pack(
    const unsigned short* __restrict__ outb,
    const float* __restrict__ sc, const float* __restrict__ sh,
    unsigned short* __restrict__ ab) {
  const int c = blockIdx.x * 256 + threadIdx.x;   // chunk id, 2048*512 total
  const int l15 = c & 15;
  const int lq  = (c >> 4) & 3;
  const int mf  = (c >> 6) & 7;
  const int kb  = c >> 9;
  const int m   = mf * 16 + l15;
  const int k   = kb * 32 + lq * 8;
  const int o   = k >> 10;
  const int hw  = k & 1023;
  float scv = sc[o], shv = sh[o];
  short8 v = *(const short8*)(outb + ((long)m * 64 + o) * 1024 + hw);
  short8 r;
  #pragma unroll
  for (int j = 0; j < 8; ++j) {
    float f = bf2f(v[j]) * scv + shv;
    r[j] = f2bf(fmaxf(f, 0.f));
  }
  *(short8*)(ab + (long)c * 8) = r;
}

// ---------------- K3: FC1 GEMM — N=128/block @ 3 blocks/CU ------------------
// R12 falsification + fill-kernel ceiling => k3 is FABRIC-bound on total
// VMEM demand (L3-A + HBM-W ~ 6.7 TB/s combined). A-demand = n_tiles x 16MB,
// so N=128 (12 tiles) halves A demand (786->594MB) -- but must keep 3
// blocks/CU (R12 lost it at 64KB LDS). Here: A 2x8KB + W 2x16KB = 48KB LDS.
// Depth-1 counted pipeline, 2 raw barriers/step:
//   STAGE(t+1) -> vmcnt(6) [12 outstanding -> drains stage(t), stage(t+1)
//   rides across the barrier] -> barrier -> COMPUTE(t) -> barrier.
// Buffer safety: STAGE(t+1) writes buf((t+1)&1), last read by compute(t-1)
// which all waves finished before the end-of-iter barrier.
__global__ __launch_bounds__(256, 3) void k3_gemm(
    const unsigned short* __restrict__ ab, const float* __restrict__ w1,
    float* __restrict__ part, int ksteps, int splits) {
  // bijective XCD swizzle: physical dispatch id -> logical block
  const int nwg = 12 * splits;
  const int chunk = nwg >> 3;                 // nwg % 8 == 0
  const int bid = blockIdx.x;
  const int lid = (bid & 7) * chunk + (bid >> 3);
  const int split = lid / 12;
  const int ntile = lid % 12;

  const int tid  = threadIdx.x;
  const int lane = tid & 63;
  const int wid  = tid >> 6;
  const int n0   = ntile * 128 + wid * 16;    // group 0; group 1 = +64
  const int l15  = lane & 15;
  const int lq   = lane >> 4;

  __shared__ unsigned short sa[2][4096];      // A: 2 x 8KB
  __shared__ float sw[2][2][4][512];          // W: 2 x 16KB

  const int kb0 = split * ksteps;
  const int kmask = ksteps - 1;               // ksteps is pow2
  const int phase = (lid * 29) & kmask;       // per-block k-rotation
  const long wsrc0 = (long)(n0 + l15) * FCIN + (long)kb0 * 32 + lq * 8;
  const long wsrc1 = wsrc0 + (long)64 * FCIN;
  const int last = ksteps - 1;

#define STAGE(T, BUF) do {                                                   \
    int Tp = ((T) + phase) & kmask;                                          \
    long gb = ((long)(kb0 + Tp) * 512 + wid * 128) * 8;                      \
    unsigned short* lb = &sa[BUF][wid * 1024];                               \
    gld16(ab + gb + (long)lane * 8, lb);                                     \
    gld16(ab + gb + 512 + (long)lane * 8, lb + 512);                         \
    const float* wg0 = w1 + wsrc0 + (long)Tp * 32;                           \
    const float* wg1 = w1 + wsrc1 + (long)Tp * 32;                           \
    float* wl0 = &sw[BUF][0][wid][0];                                        \
    float* wl1 = &sw[BUF][1][wid][0];                                        \
    gld16f(wg0, wl0);                                                        \
    gld16f(wg0 + 4, wl0 + 256);                                              \
    gld16f(wg1, wl1);                                                        \
    gld16f(wg1 + 4, wl1 + 256);                                              \
  } while (0)

#define COMPUTE(XB) do {                                                     \
    bf16x8 bfr0, bfr1;                                                       \
    {                                                                        \
      f32x4 a0 = *(const f32x4*)&sw[XB][0][wid][lane * 4];                   \
      f32x4 a1 = *(const f32x4*)&sw[XB][0][wid][256 + lane * 4];             \
      _Pragma("unroll")                                                      \
      for (int j = 0; j < 4; ++j) { bfr0[j] = f2bf(a0[j]); bfr0[4 + j] = f2bf(a1[j]); } \
    }                                                                        \
    {                                                                        \
      f32x4 a0 = *(const f32x4*)&sw[XB][1][wid][lane * 4];                   \
      f32x4 a1 = *(const f32x4*)&sw[XB][1][wid][256 + lane * 4];             \
      _Pragma("unroll")                                                      \
      for (int j = 0; j < 4; ++j) { bfr1[j] = f2bf(a0[j]); bfr1[4 + j] = f2bf(a1[j]); } \
    }                                                                        \
    __builtin_amdgcn_s_setprio(1);                                           \
    _Pragma("unroll")                                                        \
    for (int m = 0; m < 8; ++m) {                                            \
      bf16x8 afr = *(const bf16x8*)(&sa[XB][m * 512 + lane * 8]);            \
      acc[m][0] = __builtin_amdgcn_mfma_f32_16x16x32_bf16(afr, bfr0, acc[m][0], 0, 0, 0); \
      acc[m][1] = __builtin_amdgcn_mfma_f32_16x16x32_bf16(afr, bfr1, acc[m][1], 0, 0, 0); \
    }                                                                        \
    __builtin_amdgcn_s_setprio(0);                                           \
  } while (0)

  f32x4 acc[8][2];
  #pragma unroll
  for (int m = 0; m < 8; ++m) {
    acc[m][0] = (f32x4){0.f, 0.f, 0.f, 0.f};
    acc[m][1] = (f32x4){0.f, 0.f, 0.f, 0.f};
  }

  STAGE(0, 0);                                       // 6 outstanding

  for (int t = 0; t < ksteps; ++t) {
    int tn = (t + 1 <= last) ? (t + 1) : last;       // clamped dummy keeps counts uniform
    STAGE(tn, (t + 1) & 1);                          // +6 -> 12 outstanding
    asm volatile("s_waitcnt vmcnt(6)" ::: "memory"); // drain stage(t); stage(t+1) in flight
    __builtin_amdgcn_sched_barrier(0);
    __builtin_amdgcn_s_barrier();
    __builtin_amdgcn_sched_barrier(0);
    COMPUTE(t & 1);
    __builtin_amdgcn_s_barrier();                    // readers done before next STAGE overwrites
  }
  asm volatile("s_waitcnt vmcnt(0)" ::: "memory");
#undef STAGE
#undef COMPUTE

  float* pp = part + (long)split * (B_ * HID);
  #pragma unroll
  for (int m = 0; m < 8; ++m) {
    int row = m * 16 + lq * 4;
    #pragma unroll
    for (int g = 0; g < 2; ++g) {
      int col = n0 + g * 64 + l15;
      #pragma unroll
      for (int r = 0; r < 4; ++r)
        pp[(long)(row + r) * HID + col] = acc[m][g][r];
    }
  }
}

// ---------------- K4: reduce split-K + BN2 + ReLU -> h2 fp32 ----------------
__global__ __launch_bounds__(256) void k4_bn2(
    const float* __restrict__ part, const float* __restrict__ g2,
    const float* __restrict__ b2, float* __restrict__ h2, int splits) {
  const int nb = blockIdx.x;
  const int tid = threadIdx.x;
  const int nl = tid & 3;
  const int bt = tid >> 2;          // 0..63
  const int n  = nb * 4 + nl;

  float h0 = 0.f, h1 = 0.f;
  for (int s = 0; s < splits; ++s) {
    const float* pp = part + (long)s * (B_ * HID) + n;
    h0 += pp[(long)bt * HID];
    h1 += pp[(long)(bt + 64) * HID];
  }
  float s1 = h0 + h1, s2v = h0 * h0 + h1 * h1;

  __shared__ float r1[256], r2[256];
  r1[tid] = s1; r2[tid] = s2v;
  __syncthreads();
  for (int off = 32; off; off >>= 1) {
    if (bt < off) { r1[tid] += r1[tid + off * 4]; r2[tid] += r2[tid + off * 4]; }
    __syncthreads();
  }
  __shared__ float scs[4], shs[4];
  if (bt == 0) {
    float mean = r1[nl] * (1.0f / 128.f);
    float var  = r2[nl] * (1.0f / 128.f) - mean * mean;
    float rstd = 1.0f / sqrtf(var + EPSV);
    float sc = g2[n] * rstd;
    scs[nl] = sc; shs[nl] = b2[n] - mean * sc;
  }
  __syncthreads();
  float sc = scs[nl], shf = shs[nl];
  h2[(long)bt * HID + n]        = fmaxf(h0 * sc + shf, 0.f);
  h2[(long)(bt + 64) * HID + n] = fmaxf(h1 * sc + shf, 0.f);
}

// ---------------- K5: FC2 -> out [128,10] -----------------------------------
__global__ __launch_bounds__(256) void k5_fc2(
    const float* __restrict__ h2, const float* __restrict__ w2,
    float* __restrict__ out) {
  const int b = blockIdx.x;
  const int tid = threadIdx.x;
  float acc[NCLS];
  #pragma unroll
  for (int c = 0; c < NCLS; ++c) acc[c] = 0.f;
  for (int n = tid; n < HID; n += 256) {
    float hvv = h2[(long)b * HID + n];
    #pragma unroll
    for (int c = 0; c < NCLS; ++c) acc[c] += hvv * w2[c * HID + n];
  }
  #pragma unroll
  for (int off = 32; off; off >>= 1)
    #pragma unroll
    for (int c = 0; c < NCLS; ++c) acc[c] += __shfl_down(acc[c], off);
  __shared__ float ls[4][NCLS];
  int wid = tid >> 6;
  if ((tid & 63) == 0)
    for (int c = 0; c < NCLS; ++c) ls[wid][c] = acc[c];
  __syncthreads();
  if (tid < NCLS)
    out[b * NCLS + tid] = ls[0][tid] + ls[1][tid] + ls[2][tid] + ls[3][tid];
}

extern "C" void kernel_launch(void* const* d_in, const int* in_sizes, int n_in,
                              void* d_out, int out_size, void* d_ws, size_t ws_size,
                              hipStream_t stream) {
  const float* x    = (const float*)d_in[0];
  const float* lcw  = (const float*)d_in[1];
  const float* bn1g = (const float*)d_in[2];
  const float* bn1b = (const float*)d_in[3];
  const float* fc1w = (const float*)d_in[4];
  const float* bn2g = (const float*)d_in[5];
  const float* bn2b = (const float*)d_in[6];
  const float* fc2w = (const float*)d_in[7];
  float* out = (float*)d_out;

  char* ws = (char*)d_ws;
  unsigned short* outb = (unsigned short*)(ws);                              // 16 MiB
  unsigned short* ab   = (unsigned short*)(ws + (size_t)16 * 1024 * 1024);   // 16 MiB
  float* sc1 = (float*)(ws + (size_t)32 * 1024 * 1024);
  float* sh1 = sc1 + 64;
  size_t base = (size_t)32 * 1024 * 1024 + 4096;
  float* part = (float*)(ws + base);

  int splits = 64;                       // 12*64 = 768 blocks = 3/CU exactly
  size_t h2need = (size_t)B_ * HID * 4;
  while (splits > 4 && base + (size_t)splits * B_ * HID * 4 + h2need > ws_size)
    splits >>= 1;
  float* h2 = (float*)(ws + base + (size_t)splits * B_ * HID * 4);

  k1_conv<<<dim3(32, 4, 4), 256, 0, stream>>>(x, lcw, outb);
  k2_stats<<<64, 1024, 0, stream>>>(outb, bn1g, bn1b, sc1, sh1);
  k25_pack<<<4096, 256, 0, stream>>>(outb, sc1, sh1, ab);
  int ksteps = FCIN / splits / 32;
  k3_gemm<<<12 * splits, 256, 0, stream>>>(ab, fc1w, part, ksteps, splits);
  k4_bn2<<<384, 256, 0, stream>>>(part, bn2g, bn2b, h2, splits);
  k5_fc2<<<128, 256, 0, stream>>>(h2, fc2w, out);
}

// Round 15
// 202.967 us; speedup vs baseline: 1.1746x; 1.1746x over previous
//
#include <hip/hip_runtime.h>
#include <hip/hip_bf16.h>
#include <stdint.h>

#define B_   128
#define C_   3
#define H_   64
#define W_   64
#define KS   5
#define OC   64
#define OH   32
#define OW   32
#define PSZ  75          // C*K*K
#define FCIN 65536       // OC*OH*OW
#define HID  1536
#define NCLS 10
#define EPSV 1e-5f

typedef __attribute__((ext_vector_type(8))) short  bf16x8;
typedef __attribute__((ext_vector_type(8))) short  short8;
typedef __attribute__((ext_vector_type(4))) float  f32x4;

static __device__ __forceinline__ float bf2f(short u) {
  union { unsigned int i; float f; } v;
  v.i = ((unsigned int)(unsigned short)u) << 16;
  return v.f;
}
static __device__ __forceinline__ short f2bf(float f) {
  union { float f; unsigned int i; } v; v.f = f;
  unsigned int r = v.i + 0x7FFF + ((v.i >> 16) & 1);   // RNE
  return (short)(r >> 16);
}
static __device__ __forceinline__ float u2f(unsigned int u) {
  union { unsigned int i; float f; } v; v.i = u; return v.f;
}

// async global->LDS, 16B per lane; LDS dest is WAVE-UNIFORM base (+lane*16 by
// HW); the GLOBAL source is per-lane (supports arbitrary scatter).
static __device__ __forceinline__ void gld16(const unsigned short* g, unsigned short* l) {
  __builtin_amdgcn_global_load_lds(
      (const __attribute__((address_space(1))) unsigned int*)g,
      (__attribute__((address_space(3))) unsigned int*)l, 16, 0, 0);
}
static __device__ __forceinline__ void gld16f(const float* g, float* l) {
  __builtin_amdgcn_global_load_lds(
      (const __attribute__((address_space(1))) unsigned int*)g,
      (__attribute__((address_space(3))) unsigned int*)l, 16, 0, 0);
}

// ---------------- K1: LocallyConnected2d conv -> bf16 out [b][o][h*32+w] ----
// grid (32 h, 4 og, 8 zb) = 1024 blocks = 4 blocks/CU (16 waves/CU) -- R13's
// 512-block grid was OCCUPANCY-LIMITED at 2 blocks/CU (LDS 33.75KB and
// VGPR ~100 both allow 4). One 16-batch group per block; weights re-read 8x
// (157MB, hidden by the doubled TLP). Weight chunks of 5 taps x 2 oc,
// hand-pipelined one deep (spill-free).
__global__ __launch_bounds__(256, 2) void k1_conv(
    const float* __restrict__ x, const float* __restrict__ lcw,
    unsigned short* __restrict__ outb) {
  const int h  = blockIdx.x;
  const int og = blockIdx.y;
  const int bg = blockIdx.z;
  const int tid = threadIdx.x;
  const int w  = tid & 31;
  const int ot = tid >> 5;
  const int o0 = og * 16 + ot * 2;

  __shared__ unsigned short xs[16][C_][KS][72];  // bf16; gcol stored at col+2

  const float* wbaseA = lcw + (long)o0 * PSZ * 1024 + h * 32 + w;
  const float* wbaseB = wbaseA + (long)PSZ * 1024;

  const int row0 = 2 * h - 2;

  // zero borders: stored cols {0,1} and {66..71}
  if (tid < 240) {
    int t = tid;
    int r = t % KS;  t /= KS;
    int c = t % C_;
    int b = t / C_;
    *(unsigned int*)&xs[b][c][r][0]  = 0u;
    *(unsigned int*)&xs[b][c][r][66] = 0u;
    *(unsigned int*)&xs[b][c][r][68] = 0u;
    *(unsigned int*)&xs[b][c][r][70] = 0u;
  }
  // interior: 3840 float4 loads -> 2x b32 bf16-pair writes
  for (int v = tid; v < 16 * C_ * KS * 16; v += 256) {
    int col4 = v & 15;
    int t    = v >> 4;
    int r    = t % KS;  t /= KS;
    int c    = t % C_;
    int b    = t / C_;
    int grow = row0 + r;
    f32x4 val = (f32x4){0.f, 0.f, 0.f, 0.f};
    if ((unsigned)grow < 64u)
      val = *(const f32x4*)&x[(((long)(bg * 16 + b) * C_ + c) * 64 + grow) * 64 + col4 * 4];
    unsigned int p0 = ((unsigned int)(unsigned short)f2bf(val[0])) |
                      (((unsigned int)(unsigned short)f2bf(val[1])) << 16);
    unsigned int p1 = ((unsigned int)(unsigned short)f2bf(val[2])) |
                      (((unsigned int)(unsigned short)f2bf(val[3])) << 16);
    *(unsigned int*)&xs[b][c][r][2 + col4 * 4]     = p0;
    *(unsigned int*)&xs[b][c][r][2 + col4 * 4 + 2] = p1;
  }
  __syncthreads();

  float acc[2][16];
  #pragma unroll
  for (int oo = 0; oo < 2; ++oo)
    #pragma unroll
    for (int b = 0; b < 16; ++b) acc[oo][b] = 0.f;

  float wA[KS], wB[KS], nA[KS], nB[KS];
  #pragma unroll
  for (int p = 0; p < KS; ++p) {
    wA[p] = wbaseA[(long)p * 1024];
    wB[p] = wbaseB[(long)p * 1024];
  }

  #pragma unroll 1
  for (int ck = 0; ck < 15; ++ck) {
    int nk = (ck + 1 < 15) ? (ck + 1) : 14;
    #pragma unroll
    for (int p = 0; p < KS; ++p) {
      nA[p] = wbaseA[((long)nk * 5 + p) * 1024];
      nB[p] = wbaseB[((long)nk * 5 + p) * 1024];
    }
    #pragma unroll
    for (int b = 0; b < 16; ++b) {
      const unsigned int* rowp =
          (const unsigned int*)(&xs[b][0][0][0] + (long)ck * 72);
      unsigned int d0 = rowp[w];       // stored cols 2w,2w+1   (kw 0,1)
      unsigned int d1 = rowp[w + 1];   // stored cols 2w+2,2w+3 (kw 2,3)
      unsigned int d2 = rowp[w + 2];   // stored col  2w+4      (kw 4)
      float v0 = u2f(d0 << 16), v1 = u2f(d0 & 0xffff0000u);
      float v2 = u2f(d1 << 16), v3 = u2f(d1 & 0xffff0000u);
      float v4 = u2f(d2 << 16);
      acc[0][b] += wA[0] * v0 + wA[1] * v1 + wA[2] * v2 + wA[3] * v3 + wA[4] * v4;
      acc[1][b] += wB[0] * v0 + wB[1] * v1 + wB[2] * v2 + wB[3] * v3 + wB[4] * v4;
    }
    #pragma unroll
    for (int p = 0; p < KS; ++p) { wA[p] = nA[p]; wB[p] = nB[p]; }
  }

  #pragma unroll
  for (int oo = 0; oo < 2; ++oo)
    #pragma unroll
    for (int b = 0; b < 16; ++b)
      outb[((long)(bg * 16 + b) * OC + (o0 + oo)) * 1024 + h * 32 + w] =
          (unsigned short)f2bf(acc[oo][b]);
}

// ---------------- K2: BN1 batch stats -> scale/shift per channel ------------
__global__ __launch_bounds__(1024) void k2_stats(
    const unsigned short* __restrict__ outb,
    const float* __restrict__ g, const float* __restrict__ bta,
    float* __restrict__ sc, float* __restrict__ sh) {
  const int o = blockIdx.x;
  const int tid = threadIdx.x;
  float s = 0.f, s2 = 0.f;
  const int i8 = (tid & 127) * 8;
  const int bsub = tid >> 7;
  for (int pass = 0; pass < 16; ++pass) {
    int b = bsub + pass * 8;
    const short8 v = *(const short8*)(outb + (((long)b * OC + o) << 10) + i8);
    #pragma unroll
    for (int j = 0; j < 8; ++j) { float f = bf2f(v[j]); s += f; s2 += f * f; }
  }
  #pragma unroll
  for (int off = 32; off; off >>= 1) {
    s  += __shfl_down(s, off);
    s2 += __shfl_down(s2, off);
  }
  __shared__ float ls[16], ls2[16];
  int wid = tid >> 6;
  if ((tid & 63) == 0) { ls[wid] = s; ls2[wid] = s2; }
  __syncthreads();
  if (tid == 0) {
    float ts = 0.f, ts2 = 0.f;
    for (int i = 0; i < 16; ++i) { ts += ls[i]; ts2 += ls2[i]; }
    const float inv = 1.0f / (float)(B_ * 1024);
    float mean = ts * inv;
    float var  = ts2 * inv - mean * mean;
    float rstd = 1.0f / sqrtf(var + EPSV);
    float scv  = g[o] * rstd;
    sc[o] = scv;
    sh[o] = bta[o] - mean * scv;
  }
}

// ---------------- K2.5: BN1+ReLU -> SWIZZLED packed bf16 activations --------
// Chunk layout (16B units): chunk c = kb*512 + mf*64 + lq*16 + l15
//   holds A[m = mf*16+l15][k = kb*32 + lq*8 .. +7]
__global__ __launch_bounds__(256) void k25_pack(
    const unsigned short* __restrict__ outb,
    const float* __restrict__ sc, const float* __restrict__ sh,
    unsigned short* __restrict__ ab) {
  const int c = blockIdx.x * 256 + threadIdx.x;   // chunk id, 2048*512 total
  const int l15 = c & 15;
  const int lq  = (c >> 4) & 3;
  const int mf  = (c >> 6) & 7;
  const int kb  = c >> 9;
  const int m   = mf * 16 + l15;
  const int k   = kb * 32 + lq * 8;
  const int o   = k >> 10;
  const int hw  = k & 1023;
  float scv = sc[o], shv = sh[o];
  short8 v = *(const short8*)(outb + ((long)m * 64 + o) * 1024 + hw);
  short8 r;
  #pragma unroll
  for (int j = 0; j < 8; ++j) {
    float f = bf2f(v[j]) * scv + shv;
    r[j] = f2bf(fmaxf(f, 0.f));
  }
  *(short8*)(ab + (long)c * 8) = r;
}

// ---------------- K3: FC1 GEMM — counted-vmcnt depth-2 DMA pipeline ---------
// FROZEN at the R11-validated optimum (~117us): 3 buf x 16KB = 48KB LDS,
// 3 blocks/CU, vmcnt(4), per-block k-phase rotation, XCD swizzle, setprio.
// Full ledger: depth-4 null; k=64 superstep +35; N=128@2blk +50;
// N=128@3blk +29; no-rotation +40. Best of 7 structures.
__global__ __launch_bounds__(256, 3) void k3_gemm(
    const unsigned short* __restrict__ ab, const float* __restrict__ w1,
    float* __restrict__ part, int ksteps, int splits) {
  // bijective XCD swizzle: physical dispatch id -> logical block
  const int nwg = 24 * splits;
  const int chunk = nwg >> 3;                 // nwg % 8 == 0
  const int bid = blockIdx.x;
  const int lid = (bid & 7) * chunk + (bid >> 3);
  const int split = lid / 24;
  const int ntile = lid % 24;

  const int tid  = threadIdx.x;
  const int lane = tid & 63;
  const int wid  = tid >> 6;
  const int n0   = ntile * 64 + wid * 16;
  const int l15  = lane & 15;
  const int lq   = lane >> 4;

  __shared__ unsigned short sa[3][4096];   // A: 3 x 8KB
  __shared__ float sw[3][4][512];          // W: 3 x 8KB (per-wave 2KB slots)

  const int kb0 = split * ksteps;
  const int kmask = ksteps - 1;               // ksteps is pow2
  const int phase = (lid * 29) & kmask;       // per-block k-rotation
  const long wsrc = (long)(n0 + l15) * FCIN + (long)kb0 * 32 + lq * 8;
  const int last = ksteps - 1;

#define STAGE(T, BUF) do {                                                   \
    int Tp = ((T) + phase) & kmask;                                          \
    long gb = ((long)(kb0 + Tp) * 512 + wid * 128) * 8;                      \
    unsigned short* lb = &sa[BUF][wid * 1024];                               \
    gld16(ab + gb + (long)lane * 8, lb);                                     \
    gld16(ab + gb + 512 + (long)lane * 8, lb + 512);                         \
    const float* wg = w1 + wsrc + (long)Tp * 32;                             \
    float* wlb = &sw[BUF][wid][0];                                           \
    gld16f(wg, wlb);                                                         \
    gld16f(wg + 4, wlb + 256);                                               \
  } while (0)

#define COMPUTE(X) do {                                                      \
    f32x4 wv0 = *(const f32x4*)&sw[X][wid][lane * 4];                        \
    f32x4 wv1 = *(const f32x4*)&sw[X][wid][256 + lane * 4];                  \
    bf16x8 bfr;                                                              \
    _Pragma("unroll")                                                        \
    for (int j = 0; j < 4; ++j) bfr[j] = f2bf(wv0[j]);                       \
    _Pragma("unroll")                                                        \
    for (int j = 0; j < 4; ++j) bfr[4 + j] = f2bf(wv1[j]);                   \
    __builtin_amdgcn_s_setprio(1);                                           \
    _Pragma("unroll")                                                        \
    for (int m = 0; m < 8; ++m) {                                            \
      bf16x8 afr = *(const bf16x8*)(&sa[X][m * 512 + lane * 8]);             \
      acc[m] = __builtin_amdgcn_mfma_f32_16x16x32_bf16(afr, bfr, acc[m], 0, 0, 0); \
    }                                                                        \
    __builtin_amdgcn_s_setprio(0);                                           \
  } while (0)

  f32x4 acc[8];
  #pragma unroll
  for (int m = 0; m < 8; ++m) acc[m] = (f32x4){0.f, 0.f, 0.f, 0.f};

  STAGE(0, 0);
  STAGE((1 <= last ? 1 : last), 1);

  for (int t = 0; t < ksteps; ++t) {
    asm volatile("s_waitcnt vmcnt(4)" ::: "memory");   // stage(t) landed; stage(t+1) stays in flight
    __builtin_amdgcn_sched_barrier(0);
    __builtin_amdgcn_s_barrier();
    __builtin_amdgcn_sched_barrier(0);
    int tn = (t + 2 <= last) ? (t + 2) : last;         // clamped dummy keeps DMA count uniform
    STAGE(tn, (t + 2) % 3);
    COMPUTE(t % 3);
  }
#undef STAGE
#undef COMPUTE

  float* pp = part + (long)split * (B_ * HID);
  #pragma unroll
  for (int m = 0; m < 8; ++m) {
    int row = m * 16 + lq * 4;
    #pragma unroll
    for (int r = 0; r < 4; ++r)
      pp[(long)(row + r) * HID + n0 + l15] = acc[m][r];
  }
}

// ---------------- K4: reduce split-K + BN2 + ReLU -> h2 fp32 ----------------
__global__ __launch_bounds__(256) void k4_bn2(
    const float* __restrict__ part, const float* __restrict__ g2,
    const float* __restrict__ b2, float* __restrict__ h2, int splits) {
  const int nb = blockIdx.x;
  const int tid = threadIdx.x;
  const int nl = tid & 3;
  const int bt = tid >> 2;          // 0..63
  const int n  = nb * 4 + nl;

  float h0 = 0.f, h1 = 0.f;
  for (int s = 0; s < splits; ++s) {
    const float* pp = part + (long)s * (B_ * HID) + n;
    h0 += pp[(long)bt * HID];
    h1 += pp[(long)(bt + 64) * HID];
  }
  float s1 = h0 + h1, s2v = h0 * h0 + h1 * h1;

  __shared__ float r1[256], r2[256];
  r1[tid] = s1; r2[tid] = s2v;
  __syncthreads();
  for (int off = 32; off; off >>= 1) {
    if (bt < off) { r1[tid] += r1[tid + off * 4]; r2[tid] += r2[tid + off * 4]; }
    __syncthreads();
  }
  __shared__ float scs[4], shs[4];
  if (bt == 0) {
    float mean = r1[nl] * (1.0f / 128.f);
    float var  = r2[nl] * (1.0f / 128.f) - mean * mean;
    float rstd = 1.0f / sqrtf(var + EPSV);
    float sc = g2[n] * rstd;
    scs[nl] = sc; shs[nl] = b2[n] - mean * sc;
  }
  __syncthreads();
  float sc = scs[nl], shf = shs[nl];
  h2[(long)bt * HID + n]        = fmaxf(h0 * sc + shf, 0.f);
  h2[(long)(bt + 64) * HID + n] = fmaxf(h1 * sc + shf, 0.f);
}

// ---------------- K5: FC2 -> out [128,10] -----------------------------------
__global__ __launch_bounds__(256) void k5_fc2(
    const float* __restrict__ h2, const float* __restrict__ w2,
    float* __restrict__ out) {
  const int b = blockIdx.x;
  const int tid = threadIdx.x;
  float acc[NCLS];
  #pragma unroll
  for (int c = 0; c < NCLS; ++c) acc[c] = 0.f;
  for (int n = tid; n < HID; n += 256) {
    float hvv = h2[(long)b * HID + n];
    #pragma unroll
    for (int c = 0; c < NCLS; ++c) acc[c] += hvv * w2[c * HID + n];
  }
  #pragma unroll
  for (int off = 32; off; off >>= 1)
    #pragma unroll
    for (int c = 0; c < NCLS; ++c) acc[c] += __shfl_down(acc[c], off);
  __shared__ float ls[4][NCLS];
  int wid = tid >> 6;
  if ((tid & 63) == 0)
    for (int c = 0; c < NCLS; ++c) ls[wid][c] = acc[c];
  __syncthreads();
  if (tid < NCLS)
    out[b * NCLS + tid] = ls[0][tid] + ls[1][tid] + ls[2][tid] + ls[3][tid];
}

extern "C" void kernel_launch(void* const* d_in, const int* in_sizes, int n_in,
                              void* d_out, int out_size, void* d_ws, size_t ws_size,
                              hipStream_t stream) {
  const float* x    = (const float*)d_in[0];
  const float* lcw  = (const float*)d_in[1];
  const float* bn1g = (const float*)d_in[2];
  const float* bn1b = (const float*)d_in[3];
  const float* fc1w = (const float*)d_in[4];
  const float* bn2g = (const float*)d_in[5];
  const float* bn2b = (const float*)d_in[6];
  const float* fc2w = (const float*)d_in[7];
  float* out = (float*)d_out;

  char* ws = (char*)d_ws;
  unsigned short* outb = (unsigned short*)(ws);                              // 16 MiB
  unsigned short* ab   = (unsigned short*)(ws + (size_t)16 * 1024 * 1024);   // 16 MiB
  float* sc1 = (float*)(ws + (size_t)32 * 1024 * 1024);
  float* sh1 = sc1 + 64;
  size_t base = (size_t)32 * 1024 * 1024 + 4096;
  float* part = (float*)(ws + base);

  int splits = 32;                       // auto-degrade if ws too small
  size_t h2need = (size_t)B_ * HID * 4;
  while (splits > 4 && base + (size_t)splits * B_ * HID * 4 + h2need > ws_size)
    splits >>= 1;
  float* h2 = (float*)(ws + base + (size_t)splits * B_ * HID * 4);

  k1_conv<<<dim3(32, 4, 8), 256, 0, stream>>>(x, lcw, outb);
  k2_stats<<<64, 1024, 0, stream>>>(outb, bn1g, bn1b, sc1, sh1);
  k25_pack<<<4096, 256, 0, stream>>>(outb, sc1, sh1, ab);
  int ksteps = FCIN / splits / 32;
  k3_gemm<<<24 * splits, 256, 0, stream>>>(ab, fc1w, part, ksteps, splits);
  k4_bn2<<<384, 256, 0, stream>>>(part, bn2g, bn2b, h2, splits);
  k5_fc2<<<128, 256, 0, stream>>>(h2, fc2w, out);
}